// Round 4
// baseline (1950.898 us; speedup 1.0000x reference)
//
#include <hip/hip_runtime.h>
#include <hip/hip_fp16.h>
#include <cstdint>

// MessagePassing — sorted edges; edge kernel emits complete fp16 messages;
// aggregation is a pure streaming segmented sum; weights read via scalar loads.
// N=20000, E=320000. CS=64, CV=32, CM=96, WN=192, FCH=64.

#define CS 64
#define CV 32
#define CM 96
#define WN 192
#define FCH 64
#define MSGH 256   // halfs per edge slot (compacted message)

__device__ __forceinline__ float siluf(float x){ return x / (1.f + __expf(-x)); }

constexpr float INV8       = 0.125f;
constexpr float INV_SQRT32 = 0.17677669529663687f;
constexpr float INV_SQRT96 = 0.10206207261596575f;
constexpr float INV_SQRT3  = 0.5773502691896258f;

// ---------------- histogram of edge_dst ----------------
__global__ void hist_kernel(const int* __restrict__ edst, int* __restrict__ cnt, int E){
    int e = blockIdx.x*blockDim.x + threadIdx.x;
    if (e < E) atomicAdd(&cnt[edst[e]], 1);
}

// ---------------- single-block exclusive scan ----------------
__global__ void scan_kernel(const int* __restrict__ cnt, int* __restrict__ row_start,
                            int* __restrict__ cursor, int n, int E){
    __shared__ int part[1024];
    const int t = threadIdx.x;            // 1024 threads
    const int C = (n + 1023) / 1024;
    int local[32];
    int base = t*C;
    int s = 0;
    for (int j = 0; j < C && j < 32; ++j){
        int idx = base + j;
        int v = (idx < n) ? cnt[idx] : 0;
        local[j] = s; s += v;
    }
    part[t] = s;
    __syncthreads();
    for (int off = 1; off < 1024; off <<= 1){
        int v = (t >= off) ? part[t-off] : 0;
        __syncthreads();
        part[t] += v;
        __syncthreads();
    }
    int pre = (t == 0) ? 0 : part[t-1];
    for (int j = 0; j < C && j < 32; ++j){
        int idx = base + j;
        if (idx < n){ int rs = pre + local[j]; row_start[idx] = rs; cursor[idx] = rs; }
    }
    if (t == 0) row_start[n] = E;
}

// ---------------- scatter: perm + sorted eattr sidecar ----------------
__global__ void scatter_kernel(const int* __restrict__ edst, const float4* __restrict__ eattr,
                               int* __restrict__ cursor, int* __restrict__ perm,
                               float4* __restrict__ eattr_s, int E){
    int e = blockIdx.x*blockDim.x + threadIdx.x;
    if (e < E){ int p = atomicAdd(&cursor[edst[e]], 1); perm[p] = e; eattr_s[p] = eattr[e]; }
}

__global__ void isd_kernel(const int* __restrict__ cnt, float* __restrict__ isd, int n){
    int i = blockIdx.x*blockDim.x + threadIdx.x;
    if (i < n) isd[i] = rsqrtf((float)cnt[i]);
}

// ---------------- weight prep: transpose + fold 1/sqrt(64) ----------------
__global__ void wprep(const float* __restrict__ Wfa1, const float* __restrict__ Wfb1,
                      const float* __restrict__ Wfa2, const float* __restrict__ Wfb2,
                      float* __restrict__ WaT1, float* __restrict__ WbT1,
                      float* __restrict__ WaT2, float* __restrict__ WbT2){
    int t = blockIdx.x*blockDim.x + threadIdx.x;
    if (t < 4096){
        int j = t >> 6, k = t & 63;
        WaT1[j*64+k] = Wfa1[k*64+j]*INV8;
        WaT2[j*64+k] = Wfa2[k*64+j]*INV8;
    } else if (t < 4096 + 12288){
        int q = t - 4096; int o = q >> 6, k = q & 63;
        WbT1[o*64+k] = Wfb1[k*192+o]*INV8;
        WbT2[o*64+k] = Wfb2[k*192+o]*INV8;
    }
}

// ---------------- node pre-transform ----------------
template<int OS>
__global__ void node_pre(const float* __restrict__ s, int ss,
                         const float* __restrict__ v, int vs,
                         const float* __restrict__ attr,
                         const float* __restrict__ Wl1s, const float* __restrict__ Wscs,
                         const float* __restrict__ Wl1v, const float* __restrict__ Wscv,
                         float* __restrict__ f_s, float* __restrict__ sc_s,
                         float* __restrict__ f_v, float* __restrict__ sc_v, int n_nodes)
{
    constexpr int TOT = 64 + OS + 96 + 96;
    int t = blockIdx.x*blockDim.x + threadIdx.x;
    if (t >= n_nodes*TOT) return;
    int n = t / TOT, r = t - n*TOT;
    float a = attr[n];
    const float* srow = s + (size_t)n*ss;
    const float* vrow = v + (size_t)n*vs;

    if (r < 64 + OS){
        float acc = 0.f;
        if (r < 64){
            const float* col = Wl1s + r;
            #pragma unroll 8
            for (int k = 0; k < 64; ++k) acc += srow[k]*col[k*64];
            f_s[(size_t)n*64 + r] = acc * a * INV8;
        } else {
            int j = r - 64;
            const float* col = Wscs + j;
            #pragma unroll 8
            for (int k = 0; k < 64; ++k) acc += srow[k]*col[k*OS];
            sc_s[(size_t)n*OS + j] = acc * a * INV8;
        }
    } else {
        int q = r - (64 + OS);
        bool first = (q < 96);
        if (!first) q -= 96;
        int w = q/3, c = q - 3*w;
        const float* W = first ? Wl1v : Wscv;
        float acc = 0.f;
        #pragma unroll 8
        for (int u = 0; u < 32; ++u) acc += vrow[u*3 + c]*W[u*32 + w];
        float* op = (first ? f_v : sc_v) + (size_t)n*96 + q;
        *op = acc * a * INV_SQRT32;
    }
}

// ---------------- edge kernel: MLP + full message (256 fp16 per slot) ----------------
// msg layout per slot i:
//   [0,64)        : w00[o]·gs[o]·ea_s
//   [64,128)      : w01[o]·gs[o]               (agg multiplies ea_v[c])
//   [128,224)     : w10[u]·ea_s·gv[u][c]  (3u+c)
//   [224,256)     : w11[u]·(gv[u]·ea_v)/sqrt3
__global__ __launch_bounds__(256) void edge_msg(
    const int* __restrict__ perm, const int* __restrict__ esrc,
    const float* __restrict__ escal, const float4* __restrict__ eattr_s,
    const float* __restrict__ f_s, const float* __restrict__ f_v,
    const float* __restrict__ WaT, const float* __restrict__ WbT,
    __half* __restrict__ msg, int E)
{
    int i = blockIdx.x*256 + threadIdx.x;
    if (i >= E) i = E-1;               // clamp (no divergent branch -> scalar weight loads)
    const int e = perm[i];
    const int src = esrc[e];

    // edge scalars in registers
    float4 es[16];
    {
        const float4* p = reinterpret_cast<const float4*>(escal + (size_t)e*CS);
        #pragma unroll
        for (int k = 0; k < 16; ++k) es[k] = p[k];
    }

    // layer 1 (WaT rows are wave-uniform -> s_load)
    float h[FCH];
    #pragma unroll 2
    for (int j = 0; j < FCH; ++j){
        const float4* wr = reinterpret_cast<const float4*>(WaT + j*64);
        float ax=0.f, ay=0.f, az=0.f, aw=0.f;
        #pragma unroll
        for (int k = 0; k < 16; ++k){
            float4 w = wr[k];
            ax += es[k].x*w.x; ay += es[k].y*w.y; az += es[k].z*w.z; aw += es[k].w*w.w;
        }
        h[j] = siluf((ax+ay)+(az+aw));
    }

    const float4 ea = eattr_s[i];
    const float* fsrow = f_s + (size_t)src*64;
    const float* fvrow = f_v + (size_t)src*96;
    __half* mp = msg + (size_t)i*MSGH;

    auto wdot = [&](int o) -> float {
        const float4* wr = reinterpret_cast<const float4*>(WbT + o*64);
        float ax=0.f, ay=0.f, az=0.f, aw=0.f;
        #pragma unroll
        for (int k = 0; k < 16; ++k){
            float4 w = wr[k];
            ax += h[4*k+0]*w.x; ay += h[4*k+1]*w.y; az += h[4*k+2]*w.z; aw += h[4*k+3]*w.w;
        }
        return (ax+ay)+(az+aw);
    };

    // scalar paths: w00 (o<64) and w01 (64<=o<128)
    #pragma unroll 2
    for (int o = 0; o < 64; o += 4){
        float4 g4 = *reinterpret_cast<const float4*>(fsrow + o);
        float w00[4], w01[4];
        #pragma unroll
        for (int j = 0; j < 4; ++j){ w00[j] = wdot(o+j); w01[j] = wdot(64+o+j); }
        union { __half2 h2[2]; uint2 u; } pa, pb;
        pa.h2[0] = __floats2half2_rn(w00[0]*g4.x*ea.x, w00[1]*g4.y*ea.x);
        pa.h2[1] = __floats2half2_rn(w00[2]*g4.z*ea.x, w00[3]*g4.w*ea.x);
        pb.h2[0] = __floats2half2_rn(w01[0]*g4.x, w01[1]*g4.y);
        pb.h2[1] = __floats2half2_rn(w01[2]*g4.z, w01[3]*g4.w);
        *reinterpret_cast<uint2*>(mp + o)      = pa.u;
        *reinterpret_cast<uint2*>(mp + 64 + o) = pb.u;
    }

    // vector paths: w10 (128..160) and w11 (160..192)
    #pragma unroll 2
    for (int u = 0; u < 32; u += 4){
        float4 fa = *reinterpret_cast<const float4*>(fvrow + 3*u);
        float4 fb = *reinterpret_cast<const float4*>(fvrow + 3*u + 4);
        float4 fc = *reinterpret_cast<const float4*>(fvrow + 3*u + 8);
        float fv[12] = {fa.x,fa.y,fa.z,fa.w, fb.x,fb.y,fb.z,fb.w, fc.x,fc.y,fc.z,fc.w};
        float w10[4], w11[4];
        #pragma unroll
        for (int j = 0; j < 4; ++j){ w10[j] = wdot(128+u+j); w11[j] = wdot(160+u+j); }
        float s0 = w10[0]*ea.x, s1 = w10[1]*ea.x, s2 = w10[2]*ea.x, s3 = w10[3]*ea.x;
        union { __half2 h2[2]; uint2 u2; } q0, q1, q2, q3;
        q0.h2[0] = __floats2half2_rn(s0*fv[0],  s0*fv[1]);
        q0.h2[1] = __floats2half2_rn(s0*fv[2],  s1*fv[3]);
        q1.h2[0] = __floats2half2_rn(s1*fv[4],  s1*fv[5]);
        q1.h2[1] = __floats2half2_rn(s2*fv[6],  s2*fv[7]);
        q2.h2[0] = __floats2half2_rn(s2*fv[8],  s3*fv[9]);
        q2.h2[1] = __floats2half2_rn(s3*fv[10], s3*fv[11]);
        float dv0 = fv[0]*ea.y + fv[1]*ea.z + fv[2]*ea.w;
        float dv1 = fv[3]*ea.y + fv[4]*ea.z + fv[5]*ea.w;
        float dv2 = fv[6]*ea.y + fv[7]*ea.z + fv[8]*ea.w;
        float dv3 = fv[9]*ea.y + fv[10]*ea.z + fv[11]*ea.w;
        q3.h2[0] = __floats2half2_rn(w11[0]*dv0*INV_SQRT3, w11[1]*dv1*INV_SQRT3);
        q3.h2[1] = __floats2half2_rn(w11[2]*dv2*INV_SQRT3, w11[3]*dv3*INV_SQRT3);
        *reinterpret_cast<uint2*>(mp + 128 + 3*u)     = q0.u2;
        *reinterpret_cast<uint2*>(mp + 128 + 3*u + 4) = q1.u2;
        *reinterpret_cast<uint2*>(mp + 128 + 3*u + 8) = q2.u2;
        *reinterpret_cast<uint2*>(mp + 224 + u)       = q3.u2;
    }
}

// ---------------- streaming aggregation + fused node post ----------------
// 384 threads/block, wave-aligned roles:
//   t in [0,64)    A: p=t           -> asd[t]
//   t in [64,256)  C: j=t-64, o=j/3, c=j%3, p=64+o, *ea_v[c] -> avd[j]
//   t in [256,352) D: j=t-256, p=128+j -> avd[192+j]  (== avd[t-64])
//   t in [352,384) B: u=t-352, p=224+u -> asd[64+u]
template<int OS, bool FINAL>
__global__ __launch_bounds__(384) void agg_post(
    const int* __restrict__ row_start, const __half* __restrict__ msg,
    const float4* __restrict__ eattr_s,
    const float* __restrict__ isd, const float* __restrict__ attr,
    const float* __restrict__ sc_s, const float* __restrict__ sc_v,
    const float* __restrict__ W2s, const float* __restrict__ W2v,
    const float* __restrict__ W3,
    float* __restrict__ out_s, float* __restrict__ out_v)
{
    const int n = blockIdx.x;
    const int t = threadIdx.x;
    const int rs = row_start[n], re = row_start[n+1];

    int p; bool isC = false; int cidx = 0;
    if (t < 64){ p = t; }
    else if (t < 256){ int j = t-64; int o = j/3; cidx = 1 + (j - 3*o); p = 64 + o; isC = true; }
    else if (t < 352){ p = 128 + (t-256); }
    else { p = 224 + (t-352); }

    const __half* mp = msg + (size_t)rs*MSGH + p;
    const float4* eap = eattr_s + rs;
    const int cnt = re - rs;

    float acc = 0.f;
    int i = 0;
    for (; i + 4 <= cnt; i += 4){
        float m0 = __half2float(mp[(size_t)(i+0)*MSGH]);
        float m1 = __half2float(mp[(size_t)(i+1)*MSGH]);
        float m2 = __half2float(mp[(size_t)(i+2)*MSGH]);
        float m3 = __half2float(mp[(size_t)(i+3)*MSGH]);
        float f0 = 1.f, f1 = 1.f, f2 = 1.f, f3 = 1.f;
        if (isC){
            float4 e0 = eap[i+0], e1 = eap[i+1], e2 = eap[i+2], e3 = eap[i+3];
            f0 = (cidx==1)?e0.y:((cidx==2)?e0.z:e0.w);
            f1 = (cidx==1)?e1.y:((cidx==2)?e1.z:e1.w);
            f2 = (cidx==1)?e2.y:((cidx==2)?e2.z:e2.w);
            f3 = (cidx==1)?e3.y:((cidx==2)?e3.z:e3.w);
        }
        acc += m0*f0 + m1*f1 + m2*f2 + m3*f3;
    }
    for (; i < cnt; ++i){
        float m = __half2float(mp[(size_t)i*MSGH]);
        float f = 1.f;
        if (isC){
            float4 e0 = eap[i];
            f = (cidx==1)?e0.y:((cidx==2)?e0.z:e0.w);
        }
        acc += m*f;
    }
    acc *= isd[n];

    __shared__ float asd[96], avd[288], hsl[96];
    if (t < 64) asd[t] = acc;
    else if (t < 352) avd[t-64] = acc;
    else asd[64 + (t-352)] = acc;
    __syncthreads();

    const float a = attr[n];
    float ang = 0.f;
    #pragma unroll 8
    for (int k = 0; k < 96; ++k) ang += asd[k]*W3[k];
    ang *= 0.1f * a * INV_SQRT96;
    const float c_ = cosf(ang), s_ = sinf(ang);

    float hv = 0.f;
    if (t < OS){
        float d = 0.f;
        #pragma unroll 8
        for (int k = 0; k < 96; ++k) d += asd[k]*W2s[k*OS + t];
        float hs = c_*sc_s[(size_t)n*OS + t] + s_*(d * a * INV_SQRT96);
        if (FINAL) out_s[(size_t)n*160 + t] = hs;
        else       hsl[t] = hs;
    }
    if (t >= 96 && t < 192){
        const int q2 = t - 96;
        const int ww = q2/3, c2 = q2 - 3*ww;
        float d = 0.f;
        #pragma unroll 8
        for (int k = 0; k < 96; ++k) d += avd[k*3 + c2]*W2v[k*32 + ww];
        hv = c_*sc_v[(size_t)n*96 + q2] + s_*(d * a * INV_SQRT96);
        if (FINAL) out_s[(size_t)n*160 + 64 + q2] = hv;
    }
    if (!FINAL){
        __syncthreads();
        if (t < 64) out_s[(size_t)n*64 + t] = siluf(hsl[t]);
        if (t >= 96 && t < 192){
            const int q2 = t - 96;
            const int ww = q2/3;
            float sg = 1.f / (1.f + __expf(-hsl[64 + ww]));
            out_v[(size_t)n*96 + q2] = sg * hv;
        }
    }
}

// ---------------- launch ----------------
extern "C" void kernel_launch(void* const* d_in, const int* in_sizes, int n_in,
                              void* d_out, int out_size, void* d_ws, size_t ws_size,
                              hipStream_t stream)
{
    const float* nf    = (const float*)d_in[0];
    const float* nattr = (const float*)d_in[1];
    const int*   esrc  = (const int*)  d_in[2];
    const int*   edst  = (const int*)  d_in[3];
    const float* eattr = (const float*)d_in[4];
    const float* escal = (const float*)d_in[5];
    const float* p1_sc_s = (const float*)d_in[6];
    const float* p1_sc_v = (const float*)d_in[7];
    const float* p1_l1_s = (const float*)d_in[8];
    const float* p1_l1_v = (const float*)d_in[9];
    const float* p1_fa   = (const float*)d_in[10];
    const float* p1_fb   = (const float*)d_in[11];
    const float* p1_l2_s = (const float*)d_in[12];
    const float* p1_l2_v = (const float*)d_in[13];
    const float* p1_l3   = (const float*)d_in[14];
    const float* p2_sc_s = (const float*)d_in[15];
    const float* p2_sc_v = (const float*)d_in[16];
    const float* p2_l1_s = (const float*)d_in[17];
    const float* p2_l1_v = (const float*)d_in[18];
    const float* p2_fa   = (const float*)d_in[19];
    const float* p2_fb   = (const float*)d_in[20];
    const float* p2_l2_s = (const float*)d_in[21];
    const float* p2_l2_v = (const float*)d_in[22];
    const float* p2_l3   = (const float*)d_in[23];

    const int N = in_sizes[1];
    const int E = in_sizes[2];

    // ---- workspace layout (16B-aligned chunks first) ----
    char* wsb = (char*)d_ws;
    __half* msg     = (__half*)wsb;   wsb += (size_t)E*MSGH*2;   // 164 MB
    float4* eattr_s = (float4*)wsb;   wsb += (size_t)E*16;       // 5.1 MB
    float* WaT1 = (float*)wsb;        wsb += 4096*4;
    float* WbT1 = (float*)wsb;        wsb += 12288*4;
    float* WaT2 = (float*)wsb;        wsb += 4096*4;
    float* WbT2 = (float*)wsb;        wsb += 12288*4;
    float* fs   = (float*)wsb;        wsb += (size_t)N*64*4;
    float* fv   = (float*)wsb;        wsb += (size_t)N*96*4;
    float* scs  = (float*)wsb;        wsb += (size_t)N*96*4;
    float* scv  = (float*)wsb;        wsb += (size_t)N*96*4;
    float* gs   = (float*)wsb;        wsb += (size_t)N*64*4;
    float* gv   = (float*)wsb;        wsb += (size_t)N*96*4;
    float* isd  = (float*)wsb;        wsb += (size_t)N*4;
    int* cnt       = (int*)wsb;       wsb += (size_t)N*4;
    int* row_start = (int*)wsb;       wsb += (size_t)(N+1)*4;
    int* cursor    = (int*)wsb;       wsb += (size_t)N*4;
    int* perm      = (int*)wsb;       wsb += (size_t)E*4;
    // total ~215 MB

    // ---- sort edges by dst + weight prep ----
    hipMemsetAsync(cnt, 0, (size_t)N*4, stream);
    hist_kernel<<<(E+255)/256, 256, 0, stream>>>(edst, cnt, E);
    scan_kernel<<<1, 1024, 0, stream>>>(cnt, row_start, cursor, N, E);
    scatter_kernel<<<(E+255)/256, 256, 0, stream>>>(edst, (const float4*)eattr,
                                                    cursor, perm, eattr_s, E);
    isd_kernel<<<(N+255)/256, 256, 0, stream>>>(cnt, isd, N);
    wprep<<<64, 256, 0, stream>>>(p1_fa, p1_fb, p2_fa, p2_fb, WaT1, WbT1, WaT2, WbT2);

    // ---- conv1 ----
    {
        int tot = N*352;
        node_pre<96><<<(tot+255)/256, 256, 0, stream>>>(nf, 160, nf+64, 160, nattr,
            p1_l1_s, p1_sc_s, p1_l1_v, p1_sc_v, fs, scs, fv, scv, N);
    }
    edge_msg<<<(E+255)/256, 256, 0, stream>>>(perm, esrc, escal, eattr_s,
                                              fs, fv, WaT1, WbT1, msg, E);
    agg_post<96, false><<<N, 384, 0, stream>>>(row_start, msg, eattr_s,
        isd, nattr, scs, scv, p1_l2_s, p1_l2_v, p1_l3, gs, gv);

    // ---- conv2 ----
    {
        int tot = N*320;
        node_pre<64><<<(tot+255)/256, 256, 0, stream>>>(gs, 64, gv, 96, nattr,
            p2_l1_s, p2_sc_s, p2_l1_v, p2_sc_v, fs, scs, fv, scv, N);
    }
    edge_msg<<<(E+255)/256, 256, 0, stream>>>(perm, esrc, escal, eattr_s,
                                              fs, fv, WaT2, WbT2, msg, E);
    agg_post<64, true><<<N, 384, 0, stream>>>(row_start, msg, eattr_s,
        isd, nattr, scs, scv, p2_l2_s, p2_l2_v, p2_l3, (float*)d_out, nullptr);
}

// Round 5
// 1487.406 us; speedup vs baseline: 1.3116x; 1.3116x over previous
//
#include <hip/hip_runtime.h>
#include <hip/hip_fp16.h>
#include <cstdint>

// MessagePassing — sorted edges; edge kernel: LDS-staged weights + fused
// gathers + fp16 message emission; aggregation is a pure streaming sum.
// N=20000, E=320000. CS=64, CV=32, CM=96, WN=192, FCH=64.

#define CS 64
#define CV 32
#define CM 96
#define WN 192
#define FCH 64
#define MSGH 256   // halfs per edge slot (compacted message)

__device__ __forceinline__ float siluf(float x){ return x / (1.f + __expf(-x)); }

constexpr float INV8       = 0.125f;
constexpr float INV_SQRT32 = 0.17677669529663687f;
constexpr float INV_SQRT96 = 0.10206207261596575f;
constexpr float INV_SQRT3  = 0.5773502691896258f;

// ---------------- histogram of edge_dst ----------------
__global__ void hist_kernel(const int* __restrict__ edst, int* __restrict__ cnt, int E){
    int e = blockIdx.x*blockDim.x + threadIdx.x;
    if (e < E) atomicAdd(&cnt[edst[e]], 1);
}

// ---------------- single-block exclusive scan ----------------
__global__ void scan_kernel(const int* __restrict__ cnt, int* __restrict__ row_start,
                            int* __restrict__ cursor, int n, int E){
    __shared__ int part[1024];
    const int t = threadIdx.x;            // 1024 threads
    const int C = (n + 1023) / 1024;
    int local[32];
    int base = t*C;
    int s = 0;
    for (int j = 0; j < C && j < 32; ++j){
        int idx = base + j;
        int v = (idx < n) ? cnt[idx] : 0;
        local[j] = s; s += v;
    }
    part[t] = s;
    __syncthreads();
    for (int off = 1; off < 1024; off <<= 1){
        int v = (t >= off) ? part[t-off] : 0;
        __syncthreads();
        part[t] += v;
        __syncthreads();
    }
    int pre = (t == 0) ? 0 : part[t-1];
    for (int j = 0; j < C && j < 32; ++j){
        int idx = base + j;
        if (idx < n){ int rs = pre + local[j]; row_start[idx] = rs; cursor[idx] = rs; }
    }
    if (t == 0) row_start[n] = E;
}

// ---------------- scatter: perm + sorted eattr sidecar ----------------
__global__ void scatter_kernel(const int* __restrict__ edst, const float4* __restrict__ eattr,
                               int* __restrict__ cursor, int* __restrict__ perm,
                               float4* __restrict__ eattr_s, int E){
    int e = blockIdx.x*blockDim.x + threadIdx.x;
    if (e < E){ int p = atomicAdd(&cursor[edst[e]], 1); perm[p] = e; eattr_s[p] = eattr[e]; }
}

__global__ void isd_kernel(const int* __restrict__ cnt, float* __restrict__ isd, int n){
    int i = blockIdx.x*blockDim.x + threadIdx.x;
    if (i < n) isd[i] = rsqrtf((float)cnt[i]);
}

// ---------------- weight prep: transpose + fold 1/sqrt(64) ----------------
// Wcomb layout: [0,4096) = WaT (j*64+k), [4096,16384) = WbT (o*64+k)
__global__ void wprep(const float* __restrict__ Wfa1, const float* __restrict__ Wfb1,
                      const float* __restrict__ Wfa2, const float* __restrict__ Wfb2,
                      float* __restrict__ Wc1, float* __restrict__ Wc2){
    int t = blockIdx.x*blockDim.x + threadIdx.x;
    if (t < 4096){
        int j = t >> 6, k = t & 63;
        Wc1[j*64+k] = Wfa1[k*64+j]*INV8;
        Wc2[j*64+k] = Wfa2[k*64+j]*INV8;
    } else if (t < 16384){
        int q = t - 4096; int o = q >> 6, k = q & 63;
        Wc1[4096 + o*64+k] = Wfb1[k*192+o]*INV8;
        Wc2[4096 + o*64+k] = Wfb2[k*192+o]*INV8;
    }
}

// ---------------- node pre-transform ----------------
template<int OS>
__global__ void node_pre(const float* __restrict__ s, int ss,
                         const float* __restrict__ v, int vs,
                         const float* __restrict__ attr,
                         const float* __restrict__ Wl1s, const float* __restrict__ Wscs,
                         const float* __restrict__ Wl1v, const float* __restrict__ Wscv,
                         float* __restrict__ f_s, float* __restrict__ sc_s,
                         float* __restrict__ f_v, float* __restrict__ sc_v, int n_nodes)
{
    constexpr int TOT = 64 + OS + 96 + 96;
    int t = blockIdx.x*blockDim.x + threadIdx.x;
    if (t >= n_nodes*TOT) return;
    int n = t / TOT, r = t - n*TOT;
    float a = attr[n];
    const float* srow = s + (size_t)n*ss;
    const float* vrow = v + (size_t)n*vs;

    if (r < 64 + OS){
        float acc = 0.f;
        if (r < 64){
            const float* col = Wl1s + r;
            #pragma unroll 8
            for (int k = 0; k < 64; ++k) acc += srow[k]*col[k*64];
            f_s[(size_t)n*64 + r] = acc * a * INV8;
        } else {
            int j = r - 64;
            const float* col = Wscs + j;
            #pragma unroll 8
            for (int k = 0; k < 64; ++k) acc += srow[k]*col[k*OS];
            sc_s[(size_t)n*OS + j] = acc * a * INV8;
        }
    } else {
        int q = r - (64 + OS);
        bool first = (q < 96);
        if (!first) q -= 96;
        int w = q/3, c = q - 3*w;
        const float* W = first ? Wl1v : Wscv;
        float acc = 0.f;
        #pragma unroll 8
        for (int u = 0; u < 32; ++u) acc += vrow[u*3 + c]*W[u*32 + w];
        float* op = (first ? f_v : sc_v) + (size_t)n*96 + q;
        *op = acc * a * INV_SQRT32;
    }
}

// ---------------- edge kernel: LDS weights, MLP + full message ----------------
// msg layout per slot i:
//   [0,64)    : w00[o]·gs[o]·ea_s
//   [64,128)  : w01[o]·gs[o]            (agg multiplies ea_v[c])
//   [128,224) : w10[u]·ea_s·gv[u][c]  (3u+c)
//   [224,256) : w11[u]·(gv[u]·ea_v)/sqrt3
__global__ __launch_bounds__(256) void edge_msg(
    const int* __restrict__ perm, const int* __restrict__ esrc,
    const float* __restrict__ escal, const float4* __restrict__ eattr_s,
    const float* __restrict__ f_s, const float* __restrict__ f_v,
    const float* __restrict__ Wcomb,
    __half* __restrict__ msg, int E)
{
    __shared__ __align__(16) float lds[16384];   // 64 KB: WaT | WbT
    const int tid = threadIdx.x;
    {   // linear, fully-coalesced, conflict-free staging
        const float4* src4 = reinterpret_cast<const float4*>(Wcomb);
        float4* dst4 = reinterpret_cast<float4*>(lds);
        for (int i = tid; i < 4096; i += 256) dst4[i] = src4[i];
    }
    __syncthreads();

    int i = blockIdx.x*256 + tid;
    if (i >= E) i = E-1;               // clamp: uniform control flow
    const int e = perm[i];
    const int src = esrc[e];

    // edge scalars in registers
    float4 es[16];
    {
        const float4* p = reinterpret_cast<const float4*>(escal + (size_t)e*CS);
        #pragma unroll
        for (int k = 0; k < 16; ++k) es[k] = p[k];
    }

    // layer 1: wave-uniform LDS broadcast reads
    float h[FCH];
    #pragma unroll 2
    for (int j = 0; j < FCH; ++j){
        const float4* wr = reinterpret_cast<const float4*>(&lds[j*64]);
        float ax=0.f, ay=0.f, az=0.f, aw=0.f;
        #pragma unroll
        for (int k = 0; k < 16; ++k){
            float4 w = wr[k];
            ax += es[k].x*w.x; ay += es[k].y*w.y; az += es[k].z*w.z; aw += es[k].w*w.w;
        }
        h[j] = siluf((ax+ay)+(az+aw));
    }

    const float4 ea = eattr_s[i];
    const float* fsrow = f_s + (size_t)src*64;
    const float* fvrow = f_v + (size_t)src*96;
    __half* mp = msg + (size_t)i*MSGH;

    auto wdot = [&](int o) -> float {
        const float4* wr = reinterpret_cast<const float4*>(&lds[4096 + o*64]);
        float ax=0.f, ay=0.f, az=0.f, aw=0.f;
        #pragma unroll
        for (int k = 0; k < 16; ++k){
            float4 w = wr[k];
            ax += h[4*k+0]*w.x; ay += h[4*k+1]*w.y; az += h[4*k+2]*w.z; aw += h[4*k+3]*w.w;
        }
        return (ax+ay)+(az+aw);
    };

    // scalar paths: w00 (o<64) and w01 (64<=o<128)
    #pragma unroll 2
    for (int o = 0; o < 64; o += 4){
        float4 g4 = *reinterpret_cast<const float4*>(fsrow + o);
        float w00[4], w01[4];
        #pragma unroll
        for (int j = 0; j < 4; ++j){ w00[j] = wdot(o+j); w01[j] = wdot(64+o+j); }
        union { __half2 h2[2]; uint2 u; } pa, pb;
        pa.h2[0] = __floats2half2_rn(w00[0]*g4.x*ea.x, w00[1]*g4.y*ea.x);
        pa.h2[1] = __floats2half2_rn(w00[2]*g4.z*ea.x, w00[3]*g4.w*ea.x);
        pb.h2[0] = __floats2half2_rn(w01[0]*g4.x, w01[1]*g4.y);
        pb.h2[1] = __floats2half2_rn(w01[2]*g4.z, w01[3]*g4.w);
        *reinterpret_cast<uint2*>(mp + o)      = pa.u;
        *reinterpret_cast<uint2*>(mp + 64 + o) = pb.u;
    }

    // vector paths: w10 (128..160) and w11 (160..192)
    #pragma unroll 2
    for (int u = 0; u < 32; u += 4){
        float4 fa = *reinterpret_cast<const float4*>(fvrow + 3*u);
        float4 fb = *reinterpret_cast<const float4*>(fvrow + 3*u + 4);
        float4 fc = *reinterpret_cast<const float4*>(fvrow + 3*u + 8);
        float fv[12] = {fa.x,fa.y,fa.z,fa.w, fb.x,fb.y,fb.z,fb.w, fc.x,fc.y,fc.z,fc.w};
        float w10[4], w11[4];
        #pragma unroll
        for (int j = 0; j < 4; ++j){ w10[j] = wdot(128+u+j); w11[j] = wdot(160+u+j); }
        float s0 = w10[0]*ea.x, s1 = w10[1]*ea.x, s2 = w10[2]*ea.x, s3 = w10[3]*ea.x;
        union { __half2 h2[2]; uint2 u2; } q0, q1, q2, q3;
        q0.h2[0] = __floats2half2_rn(s0*fv[0],  s0*fv[1]);
        q0.h2[1] = __floats2half2_rn(s0*fv[2],  s1*fv[3]);
        q1.h2[0] = __floats2half2_rn(s1*fv[4],  s1*fv[5]);
        q1.h2[1] = __floats2half2_rn(s2*fv[6],  s2*fv[7]);
        q2.h2[0] = __floats2half2_rn(s2*fv[8],  s3*fv[9]);
        q2.h2[1] = __floats2half2_rn(s3*fv[10], s3*fv[11]);
        float dv0 = fv[0]*ea.y + fv[1]*ea.z + fv[2]*ea.w;
        float dv1 = fv[3]*ea.y + fv[4]*ea.z + fv[5]*ea.w;
        float dv2 = fv[6]*ea.y + fv[7]*ea.z + fv[8]*ea.w;
        float dv3 = fv[9]*ea.y + fv[10]*ea.z + fv[11]*ea.w;
        q3.h2[0] = __floats2half2_rn(w11[0]*dv0*INV_SQRT3, w11[1]*dv1*INV_SQRT3);
        q3.h2[1] = __floats2half2_rn(w11[2]*dv2*INV_SQRT3, w11[3]*dv3*INV_SQRT3);
        *reinterpret_cast<uint2*>(mp + 128 + 3*u)     = q0.u2;
        *reinterpret_cast<uint2*>(mp + 128 + 3*u + 4) = q1.u2;
        *reinterpret_cast<uint2*>(mp + 128 + 3*u + 8) = q2.u2;
        *reinterpret_cast<uint2*>(mp + 224 + u)       = q3.u2;
    }
}

// ---------------- streaming aggregation + fused node post ----------------
// 384 threads/block, wave-aligned roles:
//   t in [0,64)    A: p=t           -> asd[t]
//   t in [64,256)  C: j=t-64, o=j/3, c=j%3, p=64+o, *ea_v[c] -> avd[j]
//   t in [256,352) D: j=t-256, p=128+j -> avd[192+j]
//   t in [352,384) B: u=t-352, p=224+u -> asd[64+u]
template<int OS, bool FINAL>
__global__ __launch_bounds__(384) void agg_post(
    const int* __restrict__ row_start, const __half* __restrict__ msg,
    const float4* __restrict__ eattr_s,
    const float* __restrict__ isd, const float* __restrict__ attr,
    const float* __restrict__ sc_s, const float* __restrict__ sc_v,
    const float* __restrict__ W2s, const float* __restrict__ W2v,
    const float* __restrict__ W3,
    float* __restrict__ out_s, float* __restrict__ out_v)
{
    const int n = blockIdx.x;
    const int t = threadIdx.x;
    const int rs = row_start[n], re = row_start[n+1];

    int p; bool isC = false; int cidx = 0;
    if (t < 64){ p = t; }
    else if (t < 256){ int j = t-64; int o = j/3; cidx = 1 + (j - 3*o); p = 64 + o; isC = true; }
    else if (t < 352){ p = 128 + (t-256); }
    else { p = 224 + (t-352); }

    const __half* mp = msg + (size_t)rs*MSGH + p;
    const float4* eap = eattr_s + rs;
    const int cnt = re - rs;

    float acc = 0.f;
    int i = 0;
    for (; i + 4 <= cnt; i += 4){
        float m0 = __half2float(mp[(size_t)(i+0)*MSGH]);
        float m1 = __half2float(mp[(size_t)(i+1)*MSGH]);
        float m2 = __half2float(mp[(size_t)(i+2)*MSGH]);
        float m3 = __half2float(mp[(size_t)(i+3)*MSGH]);
        float f0 = 1.f, f1 = 1.f, f2 = 1.f, f3 = 1.f;
        if (isC){
            float4 e0 = eap[i+0], e1 = eap[i+1], e2 = eap[i+2], e3 = eap[i+3];
            f0 = (cidx==1)?e0.y:((cidx==2)?e0.z:e0.w);
            f1 = (cidx==1)?e1.y:((cidx==2)?e1.z:e1.w);
            f2 = (cidx==1)?e2.y:((cidx==2)?e2.z:e2.w);
            f3 = (cidx==1)?e3.y:((cidx==2)?e3.z:e3.w);
        }
        acc += m0*f0 + m1*f1 + m2*f2 + m3*f3;
    }
    for (; i < cnt; ++i){
        float m = __half2float(mp[(size_t)i*MSGH]);
        float f = 1.f;
        if (isC){
            float4 e0 = eap[i];
            f = (cidx==1)?e0.y:((cidx==2)?e0.z:e0.w);
        }
        acc += m*f;
    }
    acc *= isd[n];

    __shared__ float asd[96], avd[288], hsl[96];
    if (t < 64) asd[t] = acc;
    else if (t < 352) avd[t-64] = acc;
    else asd[64 + (t-352)] = acc;
    __syncthreads();

    const float a = attr[n];
    float ang = 0.f;
    #pragma unroll 8
    for (int k = 0; k < 96; ++k) ang += asd[k]*W3[k];
    ang *= 0.1f * a * INV_SQRT96;
    const float c_ = cosf(ang), s_ = sinf(ang);

    float hv = 0.f;
    if (t < OS){
        float d = 0.f;
        #pragma unroll 8
        for (int k = 0; k < 96; ++k) d += asd[k]*W2s[k*OS + t];
        float hs = c_*sc_s[(size_t)n*OS + t] + s_*(d * a * INV_SQRT96);
        if (FINAL) out_s[(size_t)n*160 + t] = hs;
        else       hsl[t] = hs;
    }
    if (t >= 96 && t < 192){
        const int q2 = t - 96;
        const int ww = q2/3, c2 = q2 - 3*ww;
        float d = 0.f;
        #pragma unroll 8
        for (int k = 0; k < 96; ++k) d += avd[k*3 + c2]*W2v[k*32 + ww];
        hv = c_*sc_v[(size_t)n*96 + q2] + s_*(d * a * INV_SQRT96);
        if (FINAL) out_s[(size_t)n*160 + 64 + q2] = hv;
    }
    if (!FINAL){
        __syncthreads();
        if (t < 64) out_s[(size_t)n*64 + t] = siluf(hsl[t]);
        if (t >= 96 && t < 192){
            const int q2 = t - 96;
            const int ww = q2/3;
            float sg = 1.f / (1.f + __expf(-hsl[64 + ww]));
            out_v[(size_t)n*96 + q2] = sg * hv;
        }
    }
}

// ---------------- launch ----------------
extern "C" void kernel_launch(void* const* d_in, const int* in_sizes, int n_in,
                              void* d_out, int out_size, void* d_ws, size_t ws_size,
                              hipStream_t stream)
{
    const float* nf    = (const float*)d_in[0];
    const float* nattr = (const float*)d_in[1];
    const int*   esrc  = (const int*)  d_in[2];
    const int*   edst  = (const int*)  d_in[3];
    const float* eattr = (const float*)d_in[4];
    const float* escal = (const float*)d_in[5];
    const float* p1_sc_s = (const float*)d_in[6];
    const float* p1_sc_v = (const float*)d_in[7];
    const float* p1_l1_s = (const float*)d_in[8];
    const float* p1_l1_v = (const float*)d_in[9];
    const float* p1_fa   = (const float*)d_in[10];
    const float* p1_fb   = (const float*)d_in[11];
    const float* p1_l2_s = (const float*)d_in[12];
    const float* p1_l2_v = (const float*)d_in[13];
    const float* p1_l3   = (const float*)d_in[14];
    const float* p2_sc_s = (const float*)d_in[15];
    const float* p2_sc_v = (const float*)d_in[16];
    const float* p2_l1_s = (const float*)d_in[17];
    const float* p2_l1_v = (const float*)d_in[18];
    const float* p2_fa   = (const float*)d_in[19];
    const float* p2_fb   = (const float*)d_in[20];
    const float* p2_l2_s = (const float*)d_in[21];
    const float* p2_l2_v = (const float*)d_in[22];
    const float* p2_l3   = (const float*)d_in[23];

    const int N = in_sizes[1];
    const int E = in_sizes[2];

    // ---- workspace layout (16B-aligned chunks first) ----
    char* wsb = (char*)d_ws;
    __half* msg     = (__half*)wsb;   wsb += (size_t)E*MSGH*2;   // 164 MB
    float4* eattr_s = (float4*)wsb;   wsb += (size_t)E*16;       // 5.1 MB
    float* Wc1  = (float*)wsb;        wsb += 16384*4;
    float* Wc2  = (float*)wsb;        wsb += 16384*4;
    float* fs   = (float*)wsb;        wsb += (size_t)N*64*4;
    float* fv   = (float*)wsb;        wsb += (size_t)N*96*4;
    float* scs  = (float*)wsb;        wsb += (size_t)N*96*4;
    float* scv  = (float*)wsb;        wsb += (size_t)N*96*4;
    float* gs   = (float*)wsb;        wsb += (size_t)N*64*4;
    float* gv   = (float*)wsb;        wsb += (size_t)N*96*4;
    float* isd  = (float*)wsb;        wsb += (size_t)N*4;
    int* cnt       = (int*)wsb;       wsb += (size_t)N*4;
    int* row_start = (int*)wsb;       wsb += (size_t)(N+1)*4;
    int* cursor    = (int*)wsb;       wsb += (size_t)N*4;
    int* perm      = (int*)wsb;       wsb += (size_t)E*4;
    // total ~215 MB

    // ---- sort edges by dst + weight prep ----
    hipMemsetAsync(cnt, 0, (size_t)N*4, stream);
    hist_kernel<<<(E+255)/256, 256, 0, stream>>>(edst, cnt, E);
    scan_kernel<<<1, 1024, 0, stream>>>(cnt, row_start, cursor, N, E);
    scatter_kernel<<<(E+255)/256, 256, 0, stream>>>(edst, (const float4*)eattr,
                                                    cursor, perm, eattr_s, E);
    isd_kernel<<<(N+255)/256, 256, 0, stream>>>(cnt, isd, N);
    wprep<<<64, 256, 0, stream>>>(p1_fa, p1_fb, p2_fa, p2_fb, Wc1, Wc2);

    // ---- conv1 ----
    {
        int tot = N*352;
        node_pre<96><<<(tot+255)/256, 256, 0, stream>>>(nf, 160, nf+64, 160, nattr,
            p1_l1_s, p1_sc_s, p1_l1_v, p1_sc_v, fs, scs, fv, scv, N);
    }
    edge_msg<<<(E+255)/256, 256, 0, stream>>>(perm, esrc, escal, eattr_s,
                                              fs, fv, Wc1, msg, E);
    agg_post<96, false><<<N, 384, 0, stream>>>(row_start, msg, eattr_s,
        isd, nattr, scs, scv, p1_l2_s, p1_l2_v, p1_l3, gs, gv);

    // ---- conv2 ----
    {
        int tot = N*320;
        node_pre<64><<<(tot+255)/256, 256, 0, stream>>>(gs, 64, gv, 96, nattr,
            p2_l1_s, p2_sc_s, p2_l1_v, p2_sc_v, fs, scs, fv, scv, N);
    }
    edge_msg<<<(E+255)/256, 256, 0, stream>>>(perm, esrc, escal, eattr_s,
                                              fs, fv, Wc2, msg, E);
    agg_post<64, true><<<N, 384, 0, stream>>>(row_start, msg, eattr_s,
        isd, nattr, scs, scv, p2_l2_s, p2_l2_v, p2_l3, (float*)d_out, nullptr);
}

// Round 6
// 1097.543 us; speedup vs baseline: 1.7775x; 1.3552x over previous
//
#include <hip/hip_runtime.h>
#include <hip/hip_fp16.h>
#include <cstdint>

// MessagePassing — MFMA edge-MLP (sorted output) + streaming aggregation.
// N=20000, E=320000. CS=64, CV=32, CM=96, WN=192, FCH=64.

#define CS 64
#define CV 32
#define CM 96
#define WN 192
#define FCH 64
#define WPAD 72     // padded K-stride (halfs) for LDS weight tiles

using f16x8 = __attribute__((ext_vector_type(8))) _Float16;
using f32x4 = __attribute__((ext_vector_type(4))) float;

__device__ __forceinline__ float siluf(float x){ return x / (1.f + __expf(-x)); }

constexpr float INV8       = 0.125f;
constexpr float INV_SQRT32 = 0.17677669529663687f;
constexpr float INV_SQRT96 = 0.10206207261596575f;
constexpr float INV_SQRT3  = 0.5773502691896258f;

// ---------------- histogram of edge_dst ----------------
__global__ void hist_kernel(const int* __restrict__ edst, int* __restrict__ cnt, int E){
    int e = blockIdx.x*blockDim.x + threadIdx.x;
    if (e < E) atomicAdd(&cnt[edst[e]], 1);
}

// ---------------- single-block exclusive scan ----------------
__global__ void scan_kernel(const int* __restrict__ cnt, int* __restrict__ row_start,
                            int* __restrict__ cursor, int n, int E){
    __shared__ int part[1024];
    const int t = threadIdx.x;
    const int C = (n + 1023) / 1024;
    int local[32];
    int base = t*C;
    int s = 0;
    for (int j = 0; j < C && j < 32; ++j){
        int idx = base + j;
        int v = (idx < n) ? cnt[idx] : 0;
        local[j] = s; s += v;
    }
    part[t] = s;
    __syncthreads();
    for (int off = 1; off < 1024; off <<= 1){
        int v = (t >= off) ? part[t-off] : 0;
        __syncthreads();
        part[t] += v;
        __syncthreads();
    }
    int pre = (t == 0) ? 0 : part[t-1];
    for (int j = 0; j < C && j < 32; ++j){
        int idx = base + j;
        if (idx < n){ int rs = pre + local[j]; row_start[idx] = rs; cursor[idx] = rs; }
    }
    if (t == 0) row_start[n] = E;
}

// ---------------- scatter: perm + sorted eattr/esrc sidecars ----------------
__global__ void scatter_kernel(const int* __restrict__ edst, const int* __restrict__ esrc,
                               const float4* __restrict__ eattr,
                               int* __restrict__ cursor, int* __restrict__ perm,
                               float4* __restrict__ eattr_s, int* __restrict__ esrc_s, int E){
    int e = blockIdx.x*blockDim.x + threadIdx.x;
    if (e < E){
        int p = atomicAdd(&cursor[edst[e]], 1);
        perm[p] = e; eattr_s[p] = eattr[e]; esrc_s[p] = esrc[e];
    }
}

__global__ void isd_kernel(const int* __restrict__ cnt, float* __restrict__ isd, int n){
    int i = blockIdx.x*blockDim.x + threadIdx.x;
    if (i < n) isd[i] = rsqrtf((float)cnt[i]);
}

// ---------------- weight prep: f32 -> f16, transpose, pad, fold 1/8 ----------------
// Wc layout (halfs): [0, 64*WPAD)        WaT[c*WPAD + k] = Wfa[k][c]/8
//                    [64*WPAD, +192*WPAD) WbT[o*WPAD + k] = Wfb[k][o]/8
__global__ void wprep(const float* __restrict__ Wfa1, const float* __restrict__ Wfb1,
                      const float* __restrict__ Wfa2, const float* __restrict__ Wfb2,
                      __half* __restrict__ Wc1, __half* __restrict__ Wc2){
    int t = blockIdx.x*blockDim.x + threadIdx.x;
    if (t < 64*WPAD){
        int c = t / WPAD, k = t - c*WPAD;
        float v1 = (k < 64) ? Wfa1[k*64 + c]*INV8 : 0.f;
        float v2 = (k < 64) ? Wfa2[k*64 + c]*INV8 : 0.f;
        Wc1[t] = __float2half(v1); Wc2[t] = __float2half(v2);
    } else if (t < 64*WPAD + 192*WPAD){
        int q = t - 64*WPAD; int o = q / WPAD, k = q - o*WPAD;
        float v1 = (k < 64) ? Wfb1[k*192 + o]*INV8 : 0.f;
        float v2 = (k < 64) ? Wfb2[k*192 + o]*INV8 : 0.f;
        Wc1[t] = __float2half(v1); Wc2[t] = __float2half(v2);
    }
}

// ---------------- node pre-transform ----------------
template<int OS>
__global__ void node_pre(const float* __restrict__ s, int ss,
                         const float* __restrict__ v, int vs,
                         const float* __restrict__ attr,
                         const float* __restrict__ Wl1s, const float* __restrict__ Wscs,
                         const float* __restrict__ Wl1v, const float* __restrict__ Wscv,
                         float* __restrict__ f_s, float* __restrict__ sc_s,
                         float* __restrict__ f_v, float* __restrict__ sc_v, int n_nodes)
{
    constexpr int TOT = 64 + OS + 96 + 96;
    int t = blockIdx.x*blockDim.x + threadIdx.x;
    if (t >= n_nodes*TOT) return;
    int n = t / TOT, r = t - n*TOT;
    float a = attr[n];
    const float* srow = s + (size_t)n*ss;
    const float* vrow = v + (size_t)n*vs;

    if (r < 64 + OS){
        float acc = 0.f;
        if (r < 64){
            const float* col = Wl1s + r;
            #pragma unroll 8
            for (int k = 0; k < 64; ++k) acc += srow[k]*col[k*64];
            f_s[(size_t)n*64 + r] = acc * a * INV8;
        } else {
            int j = r - 64;
            const float* col = Wscs + j;
            #pragma unroll 8
            for (int k = 0; k < 64; ++k) acc += srow[k]*col[k*OS];
            sc_s[(size_t)n*OS + j] = acc * a * INV8;
        }
    } else {
        int q = r - (64 + OS);
        bool first = (q < 96);
        if (!first) q -= 96;
        int w = q/3, c = q - 3*w;
        const float* W = first ? Wl1v : Wscv;
        float acc = 0.f;
        #pragma unroll 8
        for (int u = 0; u < 32; ++u) acc += vrow[u*3 + c]*W[u*32 + w];
        float* op = (first ? f_v : sc_v) + (size_t)n*96 + q;
        *op = acc * a * INV_SQRT32;
    }
}

// ---------------- MFMA edge MLP: w_s[i] = silu(escal[perm[i]]@Wa)@Wb ----------------
// Block = 256 thr (4 waves), 64 sorted slots per block, wave handles 16 rows.
// k-mapping for A/B frags: k = (lane>>4)*8 + j (consistent on both sides ->
// result invariant to the true HW k-permutation). C/D: col=lane&15,
// row=(lane>>4)*4+r (HW-verified mapping).
__global__ __launch_bounds__(256) void mlp_gemm(
    const int* __restrict__ perm, const float* __restrict__ escal,
    const __half* __restrict__ Wc, __half* __restrict__ w_s, int E)
{
    __shared__ __half lWa[64*WPAD];        // 9.2 KB
    __shared__ __half lWb[192*WPAD];       // 27.6 KB
    __shared__ __half hs[4][16*WPAD];      // 9.2 KB  (per-wave h tile)

    const int tid = threadIdx.x;
    // stage weights (linear uint4 copy: 36864 B = 2304 x 16B)
    {
        const uint4* src4 = reinterpret_cast<const uint4*>(Wc);
        uint4* dA = reinterpret_cast<uint4*>(lWa);
        uint4* dB = reinterpret_cast<uint4*>(lWb);
        for (int i = tid; i < (64*WPAD)/8; i += 256) dA[i] = src4[i];
        for (int i = tid; i < (192*WPAD)/8; i += 256) dB[i] = src4[(64*WPAD)/8 + i];
    }

    const int wv = tid >> 6, l = tid & 63;
    const int lm = l & 15, kg = l >> 4;
    const int base = blockIdx.x*64 + wv*16;

    // A fragments: X[base+lm][kg*8 + 0..7] for ktile 0/1 (k += 32)
    int slot = base + lm; if (slot >= E) slot = E-1;
    const int e = perm[slot];
    const float* xp = escal + (size_t)e*64 + kg*8;
    f16x8 xf0, xf1;
    {
        float4 a0 = *reinterpret_cast<const float4*>(xp);
        float4 a1 = *reinterpret_cast<const float4*>(xp + 4);
        float4 b0 = *reinterpret_cast<const float4*>(xp + 32);
        float4 b1 = *reinterpret_cast<const float4*>(xp + 36);
        xf0[0]=(_Float16)a0.x; xf0[1]=(_Float16)a0.y; xf0[2]=(_Float16)a0.z; xf0[3]=(_Float16)a0.w;
        xf0[4]=(_Float16)a1.x; xf0[5]=(_Float16)a1.y; xf0[6]=(_Float16)a1.z; xf0[7]=(_Float16)a1.w;
        xf1[0]=(_Float16)b0.x; xf1[1]=(_Float16)b0.y; xf1[2]=(_Float16)b0.z; xf1[3]=(_Float16)b0.w;
        xf1[4]=(_Float16)b1.x; xf1[5]=(_Float16)b1.y; xf1[6]=(_Float16)b1.z; xf1[7]=(_Float16)b1.w;
    }
    __syncthreads();   // weights staged

    // ---- layer 1: h = silu(X @ WaT) ----
    #pragma unroll
    for (int nt = 0; nt < 4; ++nt){
        f16x8 wa0 = *reinterpret_cast<const f16x8*>(&lWa[(nt*16 + lm)*WPAD + kg*8]);
        f16x8 wa1 = *reinterpret_cast<const f16x8*>(&lWa[(nt*16 + lm)*WPAD + 32 + kg*8]);
        f32x4 acc = {0.f,0.f,0.f,0.f};
        acc = __builtin_amdgcn_mfma_f32_16x16x32_f16(xf0, wa0, acc, 0, 0, 0);
        acc = __builtin_amdgcn_mfma_f32_16x16x32_f16(xf1, wa1, acc, 0, 0, 0);
        #pragma unroll
        for (int r = 0; r < 4; ++r){
            hs[wv][(kg*4 + r)*WPAD + nt*16 + lm] = __float2half(siluf(acc[r]));
        }
    }
    __syncthreads();   // cheap insurance: h visible (wave-private anyway)

    // ---- layer 2: W = h @ WbT ----
    f16x8 ha0 = *reinterpret_cast<const f16x8*>(&hs[wv][lm*WPAD + kg*8]);
    f16x8 ha1 = *reinterpret_cast<const f16x8*>(&hs[wv][lm*WPAD + 32 + kg*8]);
    const int orow = base + kg*4;
    #pragma unroll 4
    for (int nt = 0; nt < 12; ++nt){
        f16x8 wb0 = *reinterpret_cast<const f16x8*>(&lWb[(nt*16 + lm)*WPAD + kg*8]);
        f16x8 wb1 = *reinterpret_cast<const f16x8*>(&lWb[(nt*16 + lm)*WPAD + 32 + kg*8]);
        f32x4 acc = {0.f,0.f,0.f,0.f};
        acc = __builtin_amdgcn_mfma_f32_16x16x32_f16(ha0, wb0, acc, 0, 0, 0);
        acc = __builtin_amdgcn_mfma_f32_16x16x32_f16(ha1, wb1, acc, 0, 0, 0);
        #pragma unroll
        for (int r = 0; r < 4; ++r){
            int row = orow + r;
            if (row < E) w_s[(size_t)row*WN + nt*16 + lm] = __float2half(acc[r]);
        }
    }
}

// ---------------- streaming aggregation + fused node post ----------------
// 384 threads/block, wave-aligned roles (aggregation):
//   A: t<64        : o=t,       m = w[o]     ·fs[o]        ·ea.x      -> asd[o]
//   C: t in[64,256): j=t-64, o=j/3, c=j%3:
//                    m = w[64+o] ·fs[o]       ·ea[1+c]      -> avd[j]
//   D: t in[256,352): j2=t-256, u=j2/3:
//                    m = w[128+u]·fv[j2]      ·ea.x         -> avd[192+j2]
//   B: t in[352,384): u=t-352:
//                    m = w[160+u]·(fv[3u..]·ea.yzw)/sqrt3   -> asd[64+u]
template<int OS, bool FINAL>
__global__ __launch_bounds__(384) void agg_post(
    const int* __restrict__ row_start, const __half* __restrict__ w_s,
    const int* __restrict__ esrc_s, const float4* __restrict__ eattr_s,
    const float* __restrict__ f_s, const float* __restrict__ f_v,
    const float* __restrict__ isd, const float* __restrict__ attr,
    const float* __restrict__ sc_s, const float* __restrict__ sc_v,
    const float* __restrict__ W2s, const float* __restrict__ W2v,
    const float* __restrict__ W3,
    float* __restrict__ out_s, float* __restrict__ out_v)
{
    const int n = blockIdx.x;
    const int t = threadIdx.x;
    const int rs = row_start[n], re = row_start[n+1];
    const int cnt = re - rs;

    // role decode
    int widx, fidx, mode;   // mode: 0 = fs/fv single elem * ea comp, 1 = dot3
    float3 dummy;
    int eac = 0;            // ea component index 0..3 (x,y,z,w)
    if (t < 64){ widx = t; fidx = t; mode = 0; eac = 0; }
    else if (t < 256){ int j = t-64; int o = j/3; eac = 1 + (j - 3*o); widx = 64+o; fidx = o; mode = 0; }
    else if (t < 352){ int j2 = t-256; widx = 128 + j2/3; fidx = j2; mode = 2; eac = 0; }
    else { int u = t-352; widx = 160+u; fidx = 3*u; mode = 1; }

    float acc = 0.f;
    #pragma unroll 2
    for (int i = 0; i < cnt; ++i){
        const int src = esrc_s[rs + i];
        const float4 ea = eattr_s[rs + i];
        const float w = __half2float(w_s[(size_t)(rs + i)*WN + widx]);
        float m;
        if (mode == 0){
            float eav = (eac==0)?ea.x:((eac==1)?ea.y:((eac==2)?ea.z:ea.w));
            m = w * f_s[(size_t)src*64 + fidx] * eav;
        } else if (mode == 2){
            m = w * f_v[(size_t)src*96 + fidx] * ea.x;
        } else {
            const float* fv = f_v + (size_t)src*96 + fidx;
            float dv = fv[0]*ea.y + fv[1]*ea.z + fv[2]*ea.w;
            m = w * dv * INV_SQRT3;
        }
        acc += m;
    }
    acc *= isd[n];

    __shared__ float asd[96], avd[288], hsl[96];
    if (t < 64) asd[t] = acc;
    else if (t < 256) avd[t-64] = acc;
    else if (t < 352) avd[192 + (t-256)] = acc;
    else asd[64 + (t-352)] = acc;
    __syncthreads();

    const float a = attr[n];
    float ang = 0.f;
    #pragma unroll 8
    for (int k = 0; k < 96; ++k) ang += asd[k]*W3[k];
    ang *= 0.1f * a * INV_SQRT96;
    const float c_ = cosf(ang), s_ = sinf(ang);

    float hv = 0.f;
    if (t < OS){
        float d = 0.f;
        #pragma unroll 8
        for (int k = 0; k < 96; ++k) d += asd[k]*W2s[k*OS + t];
        float hsv = c_*sc_s[(size_t)n*OS + t] + s_*(d * a * INV_SQRT96);
        if (FINAL) out_s[(size_t)n*160 + t] = hsv;
        else       hsl[t] = hsv;
    }
    if (t >= 96 && t < 192){
        const int q2 = t - 96;
        const int ww = q2/3, c2 = q2 - 3*ww;
        float d = 0.f;
        #pragma unroll 8
        for (int k = 0; k < 96; ++k) d += avd[k*3 + c2]*W2v[k*32 + ww];
        hv = c_*sc_v[(size_t)n*96 + q2] + s_*(d * a * INV_SQRT96);
        if (FINAL) out_s[(size_t)n*160 + 64 + q2] = hv;
    }
    if (!FINAL){
        __syncthreads();
        if (t < 64) out_s[(size_t)n*64 + t] = siluf(hsl[t]);
        if (t >= 96 && t < 192){
            const int q2 = t - 96;
            const int ww = q2/3;
            float sg = 1.f / (1.f + __expf(-hsl[64 + ww]));
            out_v[(size_t)n*96 + q2] = sg * hv;
        }
    }
}

// ---------------- launch ----------------
extern "C" void kernel_launch(void* const* d_in, const int* in_sizes, int n_in,
                              void* d_out, int out_size, void* d_ws, size_t ws_size,
                              hipStream_t stream)
{
    const float* nf    = (const float*)d_in[0];
    const float* nattr = (const float*)d_in[1];
    const int*   esrc  = (const int*)  d_in[2];
    const int*   edst  = (const int*)  d_in[3];
    const float* eattr = (const float*)d_in[4];
    const float* escal = (const float*)d_in[5];
    const float* p1_sc_s = (const float*)d_in[6];
    const float* p1_sc_v = (const float*)d_in[7];
    const float* p1_l1_s = (const float*)d_in[8];
    const float* p1_l1_v = (const float*)d_in[9];
    const float* p1_fa   = (const float*)d_in[10];
    const float* p1_fb   = (const float*)d_in[11];
    const float* p1_l2_s = (const float*)d_in[12];
    const float* p1_l2_v = (const float*)d_in[13];
    const float* p1_l3   = (const float*)d_in[14];
    const float* p2_sc_s = (const float*)d_in[15];
    const float* p2_sc_v = (const float*)d_in[16];
    const float* p2_l1_s = (const float*)d_in[17];
    const float* p2_l1_v = (const float*)d_in[18];
    const float* p2_fa   = (const float*)d_in[19];
    const float* p2_fb   = (const float*)d_in[20];
    const float* p2_l2_s = (const float*)d_in[21];
    const float* p2_l2_v = (const float*)d_in[22];
    const float* p2_l3   = (const float*)d_in[23];

    const int N = in_sizes[1];
    const int E = in_sizes[2];

    // ---- workspace layout (16B-aligned blocks first) ----
    char* wsb = (char*)d_ws;
    __half* w_s     = (__half*)wsb;   wsb += (size_t)E*WN*2;        // 123 MB
    float4* eattr_s = (float4*)wsb;   wsb += (size_t)E*16;          // 5.1 MB
    __half* Wc1 = (__half*)wsb;       wsb += (size_t)(256*WPAD)*2;
    __half* Wc2 = (__half*)wsb;       wsb += (size_t)(256*WPAD)*2;
    float* fs   = (float*)wsb;        wsb += (size_t)N*64*4;
    float* fv   = (float*)wsb;        wsb += (size_t)N*96*4;
    float* scs  = (float*)wsb;        wsb += (size_t)N*96*4;
    float* scv  = (float*)wsb;        wsb += (size_t)N*96*4;
    float* gs   = (float*)wsb;        wsb += (size_t)N*64*4;
    float* gv   = (float*)wsb;        wsb += (size_t)N*96*4;
    float* isd  = (float*)wsb;        wsb += (size_t)N*4;
    int* cnt       = (int*)wsb;       wsb += (size_t)N*4;
    int* row_start = (int*)wsb;       wsb += (size_t)(N+1)*4;
    int* cursor    = (int*)wsb;       wsb += (size_t)N*4;
    int* perm      = (int*)wsb;       wsb += (size_t)E*4;
    int* esrc_s    = (int*)wsb;       wsb += (size_t)E*4;
    // total ~= 175 MB

    // ---- sort edges by dst + weight prep ----
    hipMemsetAsync(cnt, 0, (size_t)N*4, stream);
    hist_kernel<<<(E+255)/256, 256, 0, stream>>>(edst, cnt, E);
    scan_kernel<<<1, 1024, 0, stream>>>(cnt, row_start, cursor, N, E);
    scatter_kernel<<<(E+255)/256, 256, 0, stream>>>(edst, esrc, (const float4*)eattr,
                                                    cursor, perm, eattr_s, esrc_s, E);
    isd_kernel<<<(N+255)/256, 256, 0, stream>>>(cnt, isd, N);
    wprep<<<(256*WPAD+255)/256, 256, 0, stream>>>(p1_fa, p1_fb, p2_fa, p2_fb, Wc1, Wc2);

    const int gemm_grid = (E + 63)/64;

    // ---- conv1 ----
    {
        int tot = N*352;
        node_pre<96><<<(tot+255)/256, 256, 0, stream>>>(nf, 160, nf+64, 160, nattr,
            p1_l1_s, p1_sc_s, p1_l1_v, p1_sc_v, fs, scs, fv, scv, N);
    }
    mlp_gemm<<<gemm_grid, 256, 0, stream>>>(perm, escal, Wc1, w_s, E);
    agg_post<96, false><<<N, 384, 0, stream>>>(row_start, w_s, esrc_s, eattr_s,
        fs, fv, isd, nattr, scs, scv, p1_l2_s, p1_l2_v, p1_l3, gs, gv);

    // ---- conv2 ----
    {
        int tot = N*320;
        node_pre<64><<<(tot+255)/256, 256, 0, stream>>>(gs, 64, gv, 96, nattr,
            p2_l1_s, p2_sc_s, p2_l1_v, p2_sc_v, fs, scs, fv, scv, N);
    }
    mlp_gemm<<<gemm_grid, 256, 0, stream>>>(perm, escal, Wc2, w_s, E);
    agg_post<64, true><<<N, 384, 0, stream>>>(row_start, w_s, esrc_s, eattr_s,
        fs, fv, isd, nattr, scs, scv, p2_l2_s, p2_l2_v, p2_l3, (float*)d_out, nullptr);
}

// Round 7
// 807.670 us; speedup vs baseline: 2.4155x; 1.3589x over previous
//
#include <hip/hip_runtime.h>
#include <hip/hip_fp16.h>
#include <cstdint>

// MessagePassing — MFMA edge-MLP (sorted output) + chunked-LDS streaming aggregation.
// N=20000, E=320000. CS=64, CV=32, CM=96, WN=192, FCH=64.

#define CS 64
#define CV 32
#define CM 96
#define WN 192
#define FCH 64
#define WPAD 72     // padded K-stride (halfs) for LDS weight tiles
#define CHUNK 64    // edges staged per LDS batch in agg_post

using f16x8 = __attribute__((ext_vector_type(8))) _Float16;
using f32x4 = __attribute__((ext_vector_type(4))) float;

__device__ __forceinline__ float siluf(float x){ return x / (1.f + __expf(-x)); }

constexpr float INV8       = 0.125f;
constexpr float INV_SQRT32 = 0.17677669529663687f;
constexpr float INV_SQRT96 = 0.10206207261596575f;
constexpr float INV_SQRT3  = 0.5773502691896258f;

// ---------------- histogram of edge_dst ----------------
__global__ void hist_kernel(const int* __restrict__ edst, int* __restrict__ cnt, int E){
    int e = blockIdx.x*blockDim.x + threadIdx.x;
    if (e < E) atomicAdd(&cnt[edst[e]], 1);
}

// ---------------- single-block exclusive scan ----------------
__global__ void scan_kernel(const int* __restrict__ cnt, int* __restrict__ row_start,
                            int* __restrict__ cursor, int n, int E){
    __shared__ int part[1024];
    const int t = threadIdx.x;
    const int C = (n + 1023) / 1024;
    int local[32];
    int base = t*C;
    int s = 0;
    for (int j = 0; j < C && j < 32; ++j){
        int idx = base + j;
        int v = (idx < n) ? cnt[idx] : 0;
        local[j] = s; s += v;
    }
    part[t] = s;
    __syncthreads();
    for (int off = 1; off < 1024; off <<= 1){
        int v = (t >= off) ? part[t-off] : 0;
        __syncthreads();
        part[t] += v;
        __syncthreads();
    }
    int pre = (t == 0) ? 0 : part[t-1];
    for (int j = 0; j < C && j < 32; ++j){
        int idx = base + j;
        if (idx < n){ int rs = pre + local[j]; row_start[idx] = rs; cursor[idx] = rs; }
    }
    if (t == 0) row_start[n] = E;
}

// ---------------- scatter: perm + sorted eattr/esrc sidecars ----------------
__global__ void scatter_kernel(const int* __restrict__ edst, const int* __restrict__ esrc,
                               const float4* __restrict__ eattr,
                               int* __restrict__ cursor, int* __restrict__ perm,
                               float4* __restrict__ eattr_s, int* __restrict__ esrc_s, int E){
    int e = blockIdx.x*blockDim.x + threadIdx.x;
    if (e < E){
        int p = atomicAdd(&cursor[edst[e]], 1);
        perm[p] = e; eattr_s[p] = eattr[e]; esrc_s[p] = esrc[e];
    }
}

__global__ void isd_kernel(const int* __restrict__ cnt, float* __restrict__ isd, int n){
    int i = blockIdx.x*blockDim.x + threadIdx.x;
    if (i < n) isd[i] = rsqrtf((float)cnt[i]);
}

// ---------------- weight prep: f32 -> f16, transpose, pad, fold 1/8 ----------------
__global__ void wprep(const float* __restrict__ Wfa1, const float* __restrict__ Wfb1,
                      const float* __restrict__ Wfa2, const float* __restrict__ Wfb2,
                      __half* __restrict__ Wc1, __half* __restrict__ Wc2){
    int t = blockIdx.x*blockDim.x + threadIdx.x;
    if (t < 64*WPAD){
        int c = t / WPAD, k = t - c*WPAD;
        float v1 = (k < 64) ? Wfa1[k*64 + c]*INV8 : 0.f;
        float v2 = (k < 64) ? Wfa2[k*64 + c]*INV8 : 0.f;
        Wc1[t] = __float2half(v1); Wc2[t] = __float2half(v2);
    } else if (t < 64*WPAD + 192*WPAD){
        int q = t - 64*WPAD; int o = q / WPAD, k = q - o*WPAD;
        float v1 = (k < 64) ? Wfb1[k*192 + o]*INV8 : 0.f;
        float v2 = (k < 64) ? Wfb2[k*192 + o]*INV8 : 0.f;
        Wc1[t] = __float2half(v1); Wc2[t] = __float2half(v2);
    }
}

// ---------------- node pre-transform ----------------
template<int OS>
__global__ void node_pre(const float* __restrict__ s, int ss,
                         const float* __restrict__ v, int vs,
                         const float* __restrict__ attr,
                         const float* __restrict__ Wl1s, const float* __restrict__ Wscs,
                         const float* __restrict__ Wl1v, const float* __restrict__ Wscv,
                         float* __restrict__ f_s, float* __restrict__ sc_s,
                         float* __restrict__ f_v, float* __restrict__ sc_v, int n_nodes)
{
    constexpr int TOT = 64 + OS + 96 + 96;
    int t = blockIdx.x*blockDim.x + threadIdx.x;
    if (t >= n_nodes*TOT) return;
    int n = t / TOT, r = t - n*TOT;
    float a = attr[n];
    const float* srow = s + (size_t)n*ss;
    const float* vrow = v + (size_t)n*vs;

    if (r < 64 + OS){
        float acc = 0.f;
        if (r < 64){
            const float* col = Wl1s + r;
            #pragma unroll 8
            for (int k = 0; k < 64; ++k) acc += srow[k]*col[k*64];
            f_s[(size_t)n*64 + r] = acc * a * INV8;
        } else {
            int j = r - 64;
            const float* col = Wscs + j;
            #pragma unroll 8
            for (int k = 0; k < 64; ++k) acc += srow[k]*col[k*OS];
            sc_s[(size_t)n*OS + j] = acc * a * INV8;
        }
    } else {
        int q = r - (64 + OS);
        bool first = (q < 96);
        if (!first) q -= 96;
        int w = q/3, c = q - 3*w;
        const float* W = first ? Wl1v : Wscv;
        float acc = 0.f;
        #pragma unroll 8
        for (int u = 0; u < 32; ++u) acc += vrow[u*3 + c]*W[u*32 + w];
        float* op = (first ? f_v : sc_v) + (size_t)n*96 + q;
        *op = acc * a * INV_SQRT32;
    }
}

// ---------------- MFMA edge MLP ----------------
__global__ __launch_bounds__(256) void mlp_gemm(
    const int* __restrict__ perm, const float* __restrict__ escal,
    const __half* __restrict__ Wc, __half* __restrict__ w_s, int E)
{
    __shared__ __half lWa[64*WPAD];
    __shared__ __half lWb[192*WPAD];
    __shared__ __half hs[4][16*WPAD];

    const int tid = threadIdx.x;
    {
        const uint4* src4 = reinterpret_cast<const uint4*>(Wc);
        uint4* dA = reinterpret_cast<uint4*>(lWa);
        uint4* dB = reinterpret_cast<uint4*>(lWb);
        for (int i = tid; i < (64*WPAD)/8; i += 256) dA[i] = src4[i];
        for (int i = tid; i < (192*WPAD)/8; i += 256) dB[i] = src4[(64*WPAD)/8 + i];
    }

    const int wv = tid >> 6, l = tid & 63;
    const int lm = l & 15, kg = l >> 4;
    const int base = blockIdx.x*64 + wv*16;

    int slot = base + lm; if (slot >= E) slot = E-1;
    const int e = perm[slot];
    const float* xp = escal + (size_t)e*64 + kg*8;
    f16x8 xf0, xf1;
    {
        float4 a0 = *reinterpret_cast<const float4*>(xp);
        float4 a1 = *reinterpret_cast<const float4*>(xp + 4);
        float4 b0 = *reinterpret_cast<const float4*>(xp + 32);
        float4 b1 = *reinterpret_cast<const float4*>(xp + 36);
        xf0[0]=(_Float16)a0.x; xf0[1]=(_Float16)a0.y; xf0[2]=(_Float16)a0.z; xf0[3]=(_Float16)a0.w;
        xf0[4]=(_Float16)a1.x; xf0[5]=(_Float16)a1.y; xf0[6]=(_Float16)a1.z; xf0[7]=(_Float16)a1.w;
        xf1[0]=(_Float16)b0.x; xf1[1]=(_Float16)b0.y; xf1[2]=(_Float16)b0.z; xf1[3]=(_Float16)b0.w;
        xf1[4]=(_Float16)b1.x; xf1[5]=(_Float16)b1.y; xf1[6]=(_Float16)b1.z; xf1[7]=(_Float16)b1.w;
    }
    __syncthreads();

    #pragma unroll
    for (int nt = 0; nt < 4; ++nt){
        f16x8 wa0 = *reinterpret_cast<const f16x8*>(&lWa[(nt*16 + lm)*WPAD + kg*8]);
        f16x8 wa1 = *reinterpret_cast<const f16x8*>(&lWa[(nt*16 + lm)*WPAD + 32 + kg*8]);
        f32x4 acc = {0.f,0.f,0.f,0.f};
        acc = __builtin_amdgcn_mfma_f32_16x16x32_f16(xf0, wa0, acc, 0, 0, 0);
        acc = __builtin_amdgcn_mfma_f32_16x16x32_f16(xf1, wa1, acc, 0, 0, 0);
        #pragma unroll
        for (int r = 0; r < 4; ++r){
            hs[wv][(kg*4 + r)*WPAD + nt*16 + lm] = __float2half(siluf(acc[r]));
        }
    }
    __syncthreads();

    f16x8 ha0 = *reinterpret_cast<const f16x8*>(&hs[wv][lm*WPAD + kg*8]);
    f16x8 ha1 = *reinterpret_cast<const f16x8*>(&hs[wv][lm*WPAD + 32 + kg*8]);
    const int orow = base + kg*4;
    #pragma unroll 4
    for (int nt = 0; nt < 12; ++nt){
        f16x8 wb0 = *reinterpret_cast<const f16x8*>(&lWb[(nt*16 + lm)*WPAD + kg*8]);
        f16x8 wb1 = *reinterpret_cast<const f16x8*>(&lWb[(nt*16 + lm)*WPAD + 32 + kg*8]);
        f32x4 acc = {0.f,0.f,0.f,0.f};
        acc = __builtin_amdgcn_mfma_f32_16x16x32_f16(ha0, wb0, acc, 0, 0, 0);
        acc = __builtin_amdgcn_mfma_f32_16x16x32_f16(ha1, wb1, acc, 0, 0, 0);
        #pragma unroll
        for (int r = 0; r < 4; ++r){
            int row = orow + r;
            if (row < E) w_s[(size_t)row*WN + nt*16 + lm] = __float2half(acc[r]);
        }
    }
}

// ---------------- chunked streaming aggregation + fused node post ----------------
// Roles: A t<64: asd[t] += w[t]·fs[t]·ea.x
//        C t in[64,256): j=t-64,o=j/3,c=j%3: avd[j] += w[64+o]·fs[o]·ea[1+c]
//        D t in[256,352): j2=t-256: avd[192+j2] += w[128+j2/3]·fv[j2]·ea.x
//        B t in[352,384): u=t-352: asd[64+u] += w[160+u]·(fv[3u..]·ea.yzw)/sqrt3
template<int OS, bool FINAL>
__global__ __launch_bounds__(384) void agg_post(
    const int* __restrict__ row_start, const __half* __restrict__ w_s,
    const int* __restrict__ esrc_s, const float4* __restrict__ eattr_s,
    const float* __restrict__ f_s, const float* __restrict__ f_v,
    const float* __restrict__ isd, const float* __restrict__ attr,
    const float* __restrict__ sc_s, const float* __restrict__ sc_v,
    const float* __restrict__ W2s, const float* __restrict__ W2v,
    const float* __restrict__ W3,
    float* __restrict__ out_s, float* __restrict__ out_v)
{
    const int n = blockIdx.x;
    const int t = threadIdx.x;
    const int rs = row_start[n], re = row_start[n+1];

    // role decode (fixed per thread)
    int widx, fidx, mode, eac = 0;   // mode 0: fs elem * ea[eac]; 2: fv elem * ea.x; 1: dot3
    if (t < 64){ widx = t; fidx = t; mode = 0; eac = 0; }
    else if (t < 256){ int j = t-64; int o = j/3; eac = 1 + (j - 3*o); widx = 64+o; fidx = o; mode = 0; }
    else if (t < 352){ int j2 = t-256; widx = 128 + j2/3; fidx = j2; mode = 2; eac = 0; }
    else { int u = t-352; widx = 160+u; fidx = 3*u; mode = 1; }

    __shared__ int   s_src[CHUNK];
    __shared__ float s_eaf[4][CHUNK+1];   // padded: conflict-free per-lane component reads

    float acc = 0.f;
    for (int c0 = rs; c0 < re; c0 += CHUNK){
        const int m = min(CHUNK, re - c0);
        __syncthreads();                          // protect LDS reuse across chunks
        if (t < m){
            s_src[t] = esrc_s[c0 + t];
            float4 ea = eattr_s[c0 + t];
            s_eaf[0][t] = ea.x; s_eaf[1][t] = ea.y;
            s_eaf[2][t] = ea.z; s_eaf[3][t] = ea.w;
        }
        __syncthreads();

        const __half* wp = w_s + (size_t)c0*WN + widx;
        int i = 0;
        for (; i + 4 <= m; i += 4){
            // batch independent loads: 4 w, 4 src, 4 ea
            float w0 = __half2float(wp[(size_t)(i+0)*WN]);
            float w1 = __half2float(wp[(size_t)(i+1)*WN]);
            float w2 = __half2float(wp[(size_t)(i+2)*WN]);
            float w3 = __half2float(wp[(size_t)(i+3)*WN]);
            int src0 = s_src[i+0], src1 = s_src[i+1], src2 = s_src[i+2], src3 = s_src[i+3];
            if (mode == 0){
                float e0 = s_eaf[eac][i+0], e1 = s_eaf[eac][i+1];
                float e2 = s_eaf[eac][i+2], e3 = s_eaf[eac][i+3];
                float g0 = f_s[(size_t)src0*64 + fidx];
                float g1 = f_s[(size_t)src1*64 + fidx];
                float g2 = f_s[(size_t)src2*64 + fidx];
                float g3 = f_s[(size_t)src3*64 + fidx];
                acc += w0*g0*e0 + w1*g1*e1 + w2*g2*e2 + w3*g3*e3;
            } else if (mode == 2){
                float e0 = s_eaf[0][i+0], e1 = s_eaf[0][i+1];
                float e2 = s_eaf[0][i+2], e3 = s_eaf[0][i+3];
                float g0 = f_v[(size_t)src0*96 + fidx];
                float g1 = f_v[(size_t)src1*96 + fidx];
                float g2 = f_v[(size_t)src2*96 + fidx];
                float g3 = f_v[(size_t)src3*96 + fidx];
                acc += w0*g0*e0 + w1*g1*e1 + w2*g2*e2 + w3*g3*e3;
            } else {
                const float* p0 = f_v + (size_t)src0*96 + fidx;
                const float* p1 = f_v + (size_t)src1*96 + fidx;
                const float* p2 = f_v + (size_t)src2*96 + fidx;
                const float* p3 = f_v + (size_t)src3*96 + fidx;
                float d0 = p0[0]*s_eaf[1][i+0] + p0[1]*s_eaf[2][i+0] + p0[2]*s_eaf[3][i+0];
                float d1 = p1[0]*s_eaf[1][i+1] + p1[1]*s_eaf[2][i+1] + p1[2]*s_eaf[3][i+1];
                float d2 = p2[0]*s_eaf[1][i+2] + p2[1]*s_eaf[2][i+2] + p2[2]*s_eaf[3][i+2];
                float d3 = p3[0]*s_eaf[1][i+3] + p3[1]*s_eaf[2][i+3] + p3[2]*s_eaf[3][i+3];
                acc += (w0*d0 + w1*d1 + w2*d2 + w3*d3) * INV_SQRT3;
            }
        }
        for (; i < m; ++i){
            float w = __half2float(wp[(size_t)i*WN]);
            int src = s_src[i];
            if (mode == 0){
                acc += w * f_s[(size_t)src*64 + fidx] * s_eaf[eac][i];
            } else if (mode == 2){
                acc += w * f_v[(size_t)src*96 + fidx] * s_eaf[0][i];
            } else {
                const float* p = f_v + (size_t)src*96 + fidx;
                float d = p[0]*s_eaf[1][i] + p[1]*s_eaf[2][i] + p[2]*s_eaf[3][i];
                acc += w * d * INV_SQRT3;
            }
        }
    }
    acc *= isd[n];

    __shared__ float asd[96], avd[288], hsl[96];
    if (t < 64) asd[t] = acc;
    else if (t < 256) avd[t-64] = acc;
    else if (t < 352) avd[192 + (t-256)] = acc;
    else asd[64 + (t-352)] = acc;
    __syncthreads();

    const float a = attr[n];
    float ang = 0.f;
    #pragma unroll 8
    for (int k = 0; k < 96; ++k) ang += asd[k]*W3[k];
    ang *= 0.1f * a * INV_SQRT96;
    const float c_ = cosf(ang), s_ = sinf(ang);

    float hv = 0.f;
    if (t < OS){
        float d = 0.f;
        #pragma unroll 8
        for (int k = 0; k < 96; ++k) d += asd[k]*W2s[k*OS + t];
        float hsv = c_*sc_s[(size_t)n*OS + t] + s_*(d * a * INV_SQRT96);
        if (FINAL) out_s[(size_t)n*160 + t] = hsv;
        else       hsl[t] = hsv;
    }
    if (t >= 96 && t < 192){
        const int q2 = t - 96;
        const int ww = q2/3, c2 = q2 - 3*ww;
        float d = 0.f;
        #pragma unroll 8
        for (int k = 0; k < 96; ++k) d += avd[k*3 + c2]*W2v[k*32 + ww];
        hv = c_*sc_v[(size_t)n*96 + q2] + s_*(d * a * INV_SQRT96);
        if (FINAL) out_s[(size_t)n*160 + 64 + q2] = hv;
    }
    if (!FINAL){
        __syncthreads();
        if (t < 64) out_s[(size_t)n*64 + t] = siluf(hsl[t]);
        if (t >= 96 && t < 192){
            const int q2 = t - 96;
            const int ww = q2/3;
            float sg = 1.f / (1.f + __expf(-hsl[64 + ww]));
            out_v[(size_t)n*96 + q2] = sg * hv;
        }
    }
}

// ---------------- launch ----------------
extern "C" void kernel_launch(void* const* d_in, const int* in_sizes, int n_in,
                              void* d_out, int out_size, void* d_ws, size_t ws_size,
                              hipStream_t stream)
{
    const float* nf    = (const float*)d_in[0];
    const float* nattr = (const float*)d_in[1];
    const int*   esrc  = (const int*)  d_in[2];
    const int*   edst  = (const int*)  d_in[3];
    const float* eattr = (const float*)d_in[4];
    const float* escal = (const float*)d_in[5];
    const float* p1_sc_s = (const float*)d_in[6];
    const float* p1_sc_v = (const float*)d_in[7];
    const float* p1_l1_s = (const float*)d_in[8];
    const float* p1_l1_v = (const float*)d_in[9];
    const float* p1_fa   = (const float*)d_in[10];
    const float* p1_fb   = (const float*)d_in[11];
    const float* p1_l2_s = (const float*)d_in[12];
    const float* p1_l2_v = (const float*)d_in[13];
    const float* p1_l3   = (const float*)d_in[14];
    const float* p2_sc_s = (const float*)d_in[15];
    const float* p2_sc_v = (const float*)d_in[16];
    const float* p2_l1_s = (const float*)d_in[17];
    const float* p2_l1_v = (const float*)d_in[18];
    const float* p2_fa   = (const float*)d_in[19];
    const float* p2_fb   = (const float*)d_in[20];
    const float* p2_l2_s = (const float*)d_in[21];
    const float* p2_l2_v = (const float*)d_in[22];
    const float* p2_l3   = (const float*)d_in[23];

    const int N = in_sizes[1];
    const int E = in_sizes[2];

    // ---- workspace layout ----
    char* wsb = (char*)d_ws;
    __half* w_s     = (__half*)wsb;   wsb += (size_t)E*WN*2;
    float4* eattr_s = (float4*)wsb;   wsb += (size_t)E*16;
    __half* Wc1 = (__half*)wsb;       wsb += (size_t)(256*WPAD)*2;
    __half* Wc2 = (__half*)wsb;       wsb += (size_t)(256*WPAD)*2;
    float* fs   = (float*)wsb;        wsb += (size_t)N*64*4;
    float* fv   = (float*)wsb;        wsb += (size_t)N*96*4;
    float* scs  = (float*)wsb;        wsb += (size_t)N*96*4;
    float* scv  = (float*)wsb;        wsb += (size_t)N*96*4;
    float* gs   = (float*)wsb;        wsb += (size_t)N*64*4;
    float* gv   = (float*)wsb;        wsb += (size_t)N*96*4;
    float* isd  = (float*)wsb;        wsb += (size_t)N*4;
    int* cnt       = (int*)wsb;       wsb += (size_t)N*4;
    int* row_start = (int*)wsb;       wsb += (size_t)(N+1)*4;
    int* cursor    = (int*)wsb;       wsb += (size_t)N*4;
    int* perm      = (int*)wsb;       wsb += (size_t)E*4;
    int* esrc_s    = (int*)wsb;       wsb += (size_t)E*4;

    // ---- sort edges by dst + weight prep ----
    hipMemsetAsync(cnt, 0, (size_t)N*4, stream);
    hist_kernel<<<(E+255)/256, 256, 0, stream>>>(edst, cnt, E);
    scan_kernel<<<1, 1024, 0, stream>>>(cnt, row_start, cursor, N, E);
    scatter_kernel<<<(E+255)/256, 256, 0, stream>>>(edst, esrc, (const float4*)eattr,
                                                    cursor, perm, eattr_s, esrc_s, E);
    isd_kernel<<<(N+255)/256, 256, 0, stream>>>(cnt, isd, N);
    wprep<<<(256*WPAD+255)/256, 256, 0, stream>>>(p1_fa, p1_fb, p2_fa, p2_fb, Wc1, Wc2);

    const int gemm_grid = (E + 63)/64;

    // ---- conv1 ----
    {
        int tot = N*352;
        node_pre<96><<<(tot+255)/256, 256, 0, stream>>>(nf, 160, nf+64, 160, nattr,
            p1_l1_s, p1_sc_s, p1_l1_v, p1_sc_v, fs, scs, fv, scv, N);
    }
    mlp_gemm<<<gemm_grid, 256, 0, stream>>>(perm, escal, Wc1, w_s, E);
    agg_post<96, false><<<N, 384, 0, stream>>>(row_start, w_s, esrc_s, eattr_s,
        fs, fv, isd, nattr, scs, scv, p1_l2_s, p1_l2_v, p1_l3, gs, gv);

    // ---- conv2 ----
    {
        int tot = N*320;
        node_pre<64><<<(tot+255)/256, 256, 0, stream>>>(gs, 64, gv, 96, nattr,
            p2_l1_s, p2_sc_s, p2_l1_v, p2_sc_v, fs, scs, fv, scv, N);
    }
    mlp_gemm<<<gemm_grid, 256, 0, stream>>>(perm, escal, Wc2, w_s, E);
    agg_post<64, true><<<N, 384, 0, stream>>>(row_start, w_s, esrc_s, eattr_s,
        fs, fv, isd, nattr, scs, scv, p2_l2_s, p2_l2_v, p2_l3, (float*)d_out, nullptr);
}